// Round 2
// baseline (1104.812 us; speedup 1.0000x reference)
//
#include <hip/hip_runtime.h>
#include <hip/hip_bf16.h>

#define D 128  // D_IN = D_HID = D_OUT = 128

// P[r][c] = ReLU(b[c] + sum_k X[r][k] * W[k][c])
// X: [n, D] f32, W: [D, D] f32 row-major, b: [D] f32, P: [n, D] f32
template <int ROWS>
__global__ void pool_gemm(const float* __restrict__ X, const float* __restrict__ W,
                          const float* __restrict__ b, float* __restrict__ P, int n) {
    __shared__ float xs[ROWS][D];
    const int c = threadIdx.x;            // 0..127 (column)
    const int r0 = blockIdx.x * ROWS;
    for (int r = 0; r < ROWS; ++r) {
        int row = r0 + r;
        xs[r][c] = (row < n) ? X[(size_t)row * D + c] : 0.f;
    }
    __syncthreads();
    float acc[ROWS];
    const float bias = b[c];
#pragma unroll
    for (int r = 0; r < ROWS; ++r) acc[r] = bias;
#pragma unroll 4
    for (int k = 0; k < D; ++k) {
        float w = W[k * D + c];
#pragma unroll
        for (int r = 0; r < ROWS; ++r) acc[r] += xs[r][k] * w;
    }
    for (int r = 0; r < ROWS; ++r) {
        int row = r0 + r;
        if (row < n) P[(size_t)row * D + c] = fmaxf(acc[r], 0.f);
    }
}

// OUT[r][c] = ReLU(b[c] + sum_k X[r][k]*W[k][c] + sum_k A[r][k]*W[D+k][c])
// W: [2D, D] f32 (rows 0..D-1 multiply X, rows D..2D-1 multiply A)
template <int ROWS>
__global__ void upd_gemm(const float* __restrict__ X, const float* __restrict__ A,
                         const float* __restrict__ W, const float* __restrict__ b,
                         float* __restrict__ OUT, int n) {
    __shared__ float xs[ROWS][D];
    __shared__ float as[ROWS][D];
    const int c = threadIdx.x;
    const int r0 = blockIdx.x * ROWS;
    for (int r = 0; r < ROWS; ++r) {
        int row = r0 + r;
        xs[r][c] = (row < n) ? X[(size_t)row * D + c] : 0.f;
        as[r][c] = (row < n) ? A[(size_t)row * D + c] : 0.f;
    }
    __syncthreads();
    float acc[ROWS];
    const float bias = b[c];
#pragma unroll
    for (int r = 0; r < ROWS; ++r) acc[r] = bias;
#pragma unroll 2
    for (int k = 0; k < D; ++k) {
        float w0 = W[k * D + c];
        float w1 = W[(D + k) * D + c];
#pragma unroll
        for (int r = 0; r < ROWS; ++r) acc[r] += xs[r][k] * w0 + as[r][k] * w1;
    }
    for (int r = 0; r < ROWS; ++r) {
        int row = r0 + r;
        if (row < n) OUT[(size_t)row * D + c] = fmaxf(acc[r], 0.f);
    }
}

// A[dst[e]][c] = max over e of P[src[e]][c]; A zero-initialized (uint bits),
// P >= 0 so uint-compare == float-compare and init 0 == "no-edge -> 0" semantics.
__global__ void scatter_max(const int* __restrict__ src, const int* __restrict__ dst,
                            const float4* __restrict__ P4, unsigned int* __restrict__ A,
                            int nE) {
    int gid = blockIdx.x * 256 + threadIdx.x;
    int e = gid >> 5;  // 32 threads per edge, 4 floats per thread
    if (e >= nE) return;
    int q = gid & 31;
    int s = src[e];
    int d = dst[e];
    float4 v = P4[(size_t)s * 32 + q];
    unsigned int* a = &A[(size_t)d * D + q * 4];
    uint4 cur = *(const uint4*)a;  // plain read; stale-low only causes an extra atomic
    unsigned int bx = __float_as_uint(v.x);
    unsigned int by = __float_as_uint(v.y);
    unsigned int bz = __float_as_uint(v.z);
    unsigned int bw = __float_as_uint(v.w);
    if (bx > cur.x) atomicMax(&a[0], bx);
    if (by > cur.y) atomicMax(&a[1], by);
    if (bz > cur.z) atomicMax(&a[2], bz);
    if (bw > cur.w) atomicMax(&a[3], bw);
}

extern "C" void kernel_launch(void* const* d_in, const int* in_sizes, int n_in,
                              void* d_out, int out_size, void* d_ws, size_t ws_size,
                              hipStream_t stream) {
    const float* x   = (const float*)d_in[0];
    const int*   ei  = (const int*)d_in[1];
    const float* Wp1 = (const float*)d_in[2];
    const float* bp1 = (const float*)d_in[3];
    const float* Wu1 = (const float*)d_in[4];
    const float* bu1 = (const float*)d_in[5];
    const float* Wp2 = (const float*)d_in[6];
    const float* bp2 = (const float*)d_in[7];
    const float* Wu2 = (const float*)d_in[8];
    const float* bu2 = (const float*)d_in[9];
    float* out = (float*)d_out;

    const int n = in_sizes[0] / D;   // 50000 nodes
    const int E = in_sizes[1] / 2;   // 600000 edges
    const int* src = ei;
    const int* dst = ei + E;

    float* P = (float*)d_ws;                 // [n, D] pooled node features
    float* A = P + (size_t)n * D;            // [n, D] aggregated max (uint bits)
    float* H = A + (size_t)n * D;            // [n, D] layer-1 output

    constexpr int ROWS = 8;
    const int gb = (n + ROWS - 1) / ROWS;
    const int sb = (E * 32 + 255) / 256;

    // ---- layer 1 ----
    hipMemsetAsync(A, 0, (size_t)n * D * sizeof(float), stream);
    pool_gemm<ROWS><<<gb, 128, 0, stream>>>(x, Wp1, bp1, P, n);
    scatter_max<<<sb, 256, 0, stream>>>(src, dst, (const float4*)P, (unsigned int*)A, E);
    upd_gemm<ROWS><<<gb, 128, 0, stream>>>(x, A, Wu1, bu1, H, n);

    // ---- layer 2 ----
    hipMemsetAsync(A, 0, (size_t)n * D * sizeof(float), stream);
    pool_gemm<ROWS><<<gb, 128, 0, stream>>>(H, Wp2, bp2, P, n);
    scatter_max<<<sb, 256, 0, stream>>>(src, dst, (const float4*)P, (unsigned int*)A, E);
    upd_gemm<ROWS><<<gb, 128, 0, stream>>>(H, A, Wu2, bu2, out, n);
}

// Round 3
// 441.176 us; speedup vs baseline: 2.5042x; 2.5042x over previous
//
#include <hip/hip_runtime.h>
#include <hip/hip_bf16.h>

#define D 128  // D_IN = D_HID = D_OUT = 128

// ---------------- GEMMs (unchanged from round 2) ----------------

template <int ROWS>
__global__ void pool_gemm(const float* __restrict__ X, const float* __restrict__ W,
                          const float* __restrict__ b, float* __restrict__ P, int n) {
    __shared__ float xs[ROWS][D];
    const int c = threadIdx.x;            // 0..127 (column)
    const int r0 = blockIdx.x * ROWS;
    for (int r = 0; r < ROWS; ++r) {
        int row = r0 + r;
        xs[r][c] = (row < n) ? X[(size_t)row * D + c] : 0.f;
    }
    __syncthreads();
    float acc[ROWS];
    const float bias = b[c];
#pragma unroll
    for (int r = 0; r < ROWS; ++r) acc[r] = bias;
#pragma unroll 4
    for (int k = 0; k < D; ++k) {
        float w = W[k * D + c];
#pragma unroll
        for (int r = 0; r < ROWS; ++r) acc[r] += xs[r][k] * w;
    }
    for (int r = 0; r < ROWS; ++r) {
        int row = r0 + r;
        if (row < n) P[(size_t)row * D + c] = fmaxf(acc[r], 0.f);
    }
}

template <int ROWS>
__global__ void upd_gemm(const float* __restrict__ X, const float* __restrict__ A,
                         const float* __restrict__ W, const float* __restrict__ b,
                         float* __restrict__ OUT, int n) {
    __shared__ float xs[ROWS][D];
    __shared__ float as[ROWS][D];
    const int c = threadIdx.x;
    const int r0 = blockIdx.x * ROWS;
    for (int r = 0; r < ROWS; ++r) {
        int row = r0 + r;
        xs[r][c] = (row < n) ? X[(size_t)row * D + c] : 0.f;
        as[r][c] = (row < n) ? A[(size_t)row * D + c] : 0.f;
    }
    __syncthreads();
    float acc[ROWS];
    const float bias = b[c];
#pragma unroll
    for (int r = 0; r < ROWS; ++r) acc[r] = bias;
#pragma unroll 2
    for (int k = 0; k < D; ++k) {
        float w0 = W[k * D + c];
        float w1 = W[(D + k) * D + c];
#pragma unroll
        for (int r = 0; r < ROWS; ++r) acc[r] += xs[r][k] * w0 + as[r][k] * w1;
    }
    for (int r = 0; r < ROWS; ++r) {
        int row = r0 + r;
        if (row < n) OUT[(size_t)row * D + c] = fmaxf(acc[r], 0.f);
    }
}

// ---------------- CSR build (once per launch; edges shared by both layers) ----

__global__ void hist_kernel(const int* __restrict__ dst, int* __restrict__ deg, int E) {
    int e = blockIdx.x * 256 + threadIdx.x;
    if (e < E) atomicAdd(&deg[dst[e]], 1);
}

// per-block inclusive scan of deg -> scanned, block totals -> partials
__global__ void scan1_kernel(const int* __restrict__ deg, int* __restrict__ scanned,
                             int* __restrict__ partials, int n) {
    __shared__ int s[256];
    const int t = threadIdx.x;
    const int i = blockIdx.x * 256 + t;
    s[t] = (i < n) ? deg[i] : 0;
    __syncthreads();
    for (int off = 1; off < 256; off <<= 1) {
        int add = (t >= off) ? s[t - off] : 0;
        __syncthreads();
        s[t] += add;
        __syncthreads();
    }
    if (i < n) scanned[i] = s[t];
    if (t == 255) partials[blockIdx.x] = s[255];
}

// single-block inclusive scan of partials (nb <= 256)
__global__ void scan2_kernel(int* __restrict__ partials, int nb) {
    __shared__ int s[256];
    const int t = threadIdx.x;
    s[t] = (t < nb) ? partials[t] : 0;
    __syncthreads();
    for (int off = 1; off < 256; off <<= 1) {
        int add = (t >= off) ? s[t - off] : 0;
        __syncthreads();
        s[t] += add;
        __syncthreads();
    }
    if (t < nb) partials[t] = s[t];
}

// exclusive row starts + cursor init
__global__ void finalize_kernel(const int* __restrict__ deg, const int* __restrict__ scanned,
                                const int* __restrict__ partials, int* __restrict__ rowstart,
                                int* __restrict__ cursor, int n) {
    const int i = blockIdx.x * 256 + threadIdx.x;
    if (i >= n) return;
    const int b = blockIdx.x;
    int off = (b > 0) ? partials[b - 1] : 0;
    int excl = scanned[i] - deg[i] + off;
    rowstart[i] = excl;
    cursor[i] = excl;
}

__global__ void bucket_kernel(const int* __restrict__ src, const int* __restrict__ dst,
                              int* __restrict__ cursor, int* __restrict__ srcs, int E) {
    int e = blockIdx.x * 256 + threadIdx.x;
    if (e < E) {
        int pos = atomicAdd(&cursor[dst[e]], 1);
        srcs[pos] = src[e];
    }
}

// ---------------- aggregation: register max over CSR row, no atomics ----------
// 32 threads per node, float4 per thread. deg==0 -> zeros (matches isfinite->0).
__global__ void aggregate_kernel(const int* __restrict__ rowstart, const int* __restrict__ deg,
                                 const int* __restrict__ srcs, const float4* __restrict__ P4,
                                 float4* __restrict__ A4, int n) {
    int gid = blockIdx.x * 256 + threadIdx.x;
    int node = gid >> 5;
    if (node >= n) return;
    int q = gid & 31;
    int start = rowstart[node];
    int d = deg[node];
    float4 m = make_float4(0.f, 0.f, 0.f, 0.f);
    if (d > 0) {
        int s0 = srcs[start];
        float4 v = P4[(size_t)s0 * 32 + q];
        for (int j = 1; j < d; ++j) {
            int s1 = srcs[start + j];                 // broadcast load
            float4 v1 = P4[(size_t)s1 * 32 + q];      // issue next gather before max
            m.x = fmaxf(m.x, v.x); m.y = fmaxf(m.y, v.y);
            m.z = fmaxf(m.z, v.z); m.w = fmaxf(m.w, v.w);
            v = v1;
        }
        m.x = fmaxf(m.x, v.x); m.y = fmaxf(m.y, v.y);
        m.z = fmaxf(m.z, v.z); m.w = fmaxf(m.w, v.w);
    }
    A4[(size_t)node * 32 + q] = m;
}

extern "C" void kernel_launch(void* const* d_in, const int* in_sizes, int n_in,
                              void* d_out, int out_size, void* d_ws, size_t ws_size,
                              hipStream_t stream) {
    const float* x   = (const float*)d_in[0];
    const int*   ei  = (const int*)d_in[1];
    const float* Wp1 = (const float*)d_in[2];
    const float* bp1 = (const float*)d_in[3];
    const float* Wu1 = (const float*)d_in[4];
    const float* bu1 = (const float*)d_in[5];
    const float* Wp2 = (const float*)d_in[6];
    const float* bp2 = (const float*)d_in[7];
    const float* Wu2 = (const float*)d_in[8];
    const float* bu2 = (const float*)d_in[9];
    float* out = (float*)d_out;

    const int n = in_sizes[0] / D;   // 50000 nodes
    const int E = in_sizes[1] / 2;   // 600000 edges
    const int* src = ei;
    const int* dst = ei + E;

    // workspace layout
    float* P = (float*)d_ws;                         // [n, D]
    float* A = P + (size_t)n * D;                    // [n, D]
    float* H = A + (size_t)n * D;                    // [n, D]
    int* ibase    = (int*)(H + (size_t)n * D);
    int* deg      = ibase;                           // [n]
    int* scanned  = deg + n;                         // [n]
    int* rowstart = scanned + n;                     // [n]
    int* cursor   = rowstart + n;                    // [n]
    int* partials = cursor + n;                      // [256]
    int* srcs     = partials + 256;                  // [E]

    constexpr int ROWS = 8;
    const int gb = (n + ROWS - 1) / ROWS;
    const int nb = (n + 255) / 256;
    const int eb = (E + 255) / 256;
    const int ab = (n * 32 + 255) / 256;

    // ---- CSR build (edges identical for both layers) ----
    hipMemsetAsync(deg, 0, (size_t)n * sizeof(int), stream);
    hist_kernel<<<eb, 256, 0, stream>>>(dst, deg, E);
    scan1_kernel<<<nb, 256, 0, stream>>>(deg, scanned, partials, n);
    scan2_kernel<<<1, 256, 0, stream>>>(partials, nb);
    finalize_kernel<<<nb, 256, 0, stream>>>(deg, scanned, partials, rowstart, cursor, n);
    bucket_kernel<<<eb, 256, 0, stream>>>(src, dst, cursor, srcs, E);

    // ---- layer 1 ----
    pool_gemm<ROWS><<<gb, 128, 0, stream>>>(x, Wp1, bp1, P, n);
    aggregate_kernel<<<ab, 256, 0, stream>>>(rowstart, deg, srcs, (const float4*)P, (float4*)A, n);
    upd_gemm<ROWS><<<gb, 128, 0, stream>>>(x, A, Wu1, bu1, H, n);

    // ---- layer 2 ----
    pool_gemm<ROWS><<<gb, 128, 0, stream>>>(H, Wp2, bp2, P, n);
    aggregate_kernel<<<ab, 256, 0, stream>>>(rowstart, deg, srcs, (const float4*)P, (float4*)A, n);
    upd_gemm<ROWS><<<gb, 128, 0, stream>>>(H, A, Wu2, bu2, out, n);
}

// Round 4
// 188.013 us; speedup vs baseline: 5.8763x; 2.3465x over previous
//
#include <hip/hip_runtime.h>

#define D 128  // D_IN = D_HID = D_OUT = 128

typedef __attribute__((ext_vector_type(8))) short bf16x8;
typedef __attribute__((ext_vector_type(4))) float f32x4;
typedef __attribute__((ext_vector_type(8))) unsigned short u16x8;

__device__ __forceinline__ unsigned short f2bf(float f) {   // RNE f32->bf16
    unsigned u = __float_as_uint(f);
    u = u + 0x7fffu + ((u >> 16) & 1u);
    return (unsigned short)(u >> 16);
}

// ---- f32 -> bf16 conversion (x only), 4 elems/thread ----
__global__ void conv_bf16(const float4* __restrict__ in, ushort4* __restrict__ out, int n4) {
    int i = blockIdx.x * 256 + threadIdx.x;
    if (i >= n4) return;
    float4 v = in[i];
    ushort4 o;
    o.x = f2bf(v.x); o.y = f2bf(v.y); o.z = f2bf(v.z); o.w = f2bf(v.w);
    out[i] = o;
}

// ---- pack W [K,128] f32 row-major into per-lane MFMA B-fragment order ----
// out[(((kt*8)+nt)*64 + l)*8 + j] = bf16(W[(kt*32 + (l>>4)*8 + j)*128 + nt*16 + (l&15)])
__global__ void pack_w(const float* __restrict__ W, unsigned short* __restrict__ out) {
    const int kt = blockIdx.x >> 3, nt = blockIdx.x & 7, l = threadIdx.x;
    u16x8 pv;
#pragma unroll
    for (int j = 0; j < 8; ++j)
        pv[j] = f2bf(W[(size_t)(kt * 32 + (l >> 4) * 8 + j) * D + nt * 16 + (l & 15)]);
    *(u16x8*)&out[((size_t)blockIdx.x * 64 + l) * 8] = pv;
}

// ---- MFMA GEMM: OUT[r][c] = ReLU(bias[c] + sum_k X[r][k] W[k][c]) ----
// KT = K/32. For KT==8 (update GEMM), kt 0..3 reads X0, kt 4..7 reads X1 (concat).
// Wp is packed by pack_w. Output bf16 (F32OUT=false) or f32 (true).
template <int KT, bool F32OUT>
__launch_bounds__(256)
__global__ void mfma_gemm(const unsigned short* __restrict__ X0,
                          const unsigned short* __restrict__ X1,
                          const unsigned short* __restrict__ Wp,
                          const float* __restrict__ bias,
                          void* __restrict__ outp, int n) {
    __shared__ float lds[4][16 * D];           // 32 KB: per-wave epilogue tile
    const int tid = threadIdx.x;
    const int w = tid >> 6, l = tid & 63;
    const int r0 = blockIdx.x * 64 + w * 16;   // this wave's 16-row strip
    const int lrow = l & 15, lk = l >> 4;
    int arow = r0 + lrow;
    if (arow > n - 1) arow = n - 1;            // clamp; store is guarded

    f32x4 acc[8];
#pragma unroll
    for (int nt = 0; nt < 8; ++nt) {
        float bv = bias[nt * 16 + lrow];       // lane's column is nt*16+lrow
        acc[nt] = (f32x4){bv, bv, bv, bv};
    }

#pragma unroll
    for (int kt = 0; kt < KT; ++kt) {
        const unsigned short* xs = (KT == 8 && kt >= 4) ? X1 : X0;
        const int ktl = (KT == 8 && kt >= 4) ? kt - 4 : kt;
        bf16x8 a = *(const bf16x8*)(xs + (size_t)arow * D + ktl * 32 + lk * 8);
#pragma unroll
        for (int nt = 0; nt < 8; ++nt) {
            bf16x8 b = *(const bf16x8*)(Wp + (((size_t)kt * 8 + nt) * 64 + l) * 8);
            acc[nt] = __builtin_amdgcn_mfma_f32_16x16x32_bf16(a, b, acc[nt], 0, 0, 0);
        }
    }

    // epilogue: ReLU, transpose via LDS, coalesced 16B stores
    if (F32OUT) {
        float* t = lds[w];
#pragma unroll
        for (int nt = 0; nt < 8; ++nt)
#pragma unroll
            for (int r = 0; r < 4; ++r)
                t[(lk * 4 + r) * D + nt * 16 + lrow] = fmaxf(acc[nt][r], 0.f);
        __syncthreads();
        float* O = (float*)outp;
#pragma unroll
        for (int p = 0; p < 8; ++p) {
            int flat = p * 256 + l * 4;
            int rt = flat >> 7, col = flat & (D - 1);
            int grow = r0 + rt;
            if (grow < n)
                *(float4*)(O + (size_t)grow * D + col) = *(const float4*)(t + flat);
        }
    } else {
        unsigned short* t = (unsigned short*)lds[w];
#pragma unroll
        for (int nt = 0; nt < 8; ++nt)
#pragma unroll
            for (int r = 0; r < 4; ++r)
                t[(lk * 4 + r) * D + nt * 16 + lrow] = f2bf(fmaxf(acc[nt][r], 0.f));
        __syncthreads();
        unsigned short* O = (unsigned short*)outp;
#pragma unroll
        for (int p = 0; p < 4; ++p) {
            int flat = p * 512 + l * 8;
            int rt = flat >> 7, col = flat & (D - 1);
            int grow = r0 + rt;
            if (grow < n)
                *(u16x8*)(O + (size_t)grow * D + col) = *(const u16x8*)(t + flat);
        }
    }
}

// ---------------- CSR build (edges shared by both layers) ----------------

__global__ void hist_kernel(const int* __restrict__ dst, int* __restrict__ deg, int E) {
    int e = blockIdx.x * 256 + threadIdx.x;
    if (e < E) atomicAdd(&deg[dst[e]], 1);
}

__global__ void scan1_kernel(const int* __restrict__ deg, int* __restrict__ scanned,
                             int* __restrict__ partials, int n) {
    __shared__ int s[256];
    const int t = threadIdx.x;
    const int i = blockIdx.x * 256 + t;
    s[t] = (i < n) ? deg[i] : 0;
    __syncthreads();
    for (int off = 1; off < 256; off <<= 1) {
        int add = (t >= off) ? s[t - off] : 0;
        __syncthreads();
        s[t] += add;
        __syncthreads();
    }
    if (i < n) scanned[i] = s[t];
    if (t == 255) partials[blockIdx.x] = s[255];
}

__global__ void scan2_kernel(int* __restrict__ partials, int nb) {
    __shared__ int s[256];
    const int t = threadIdx.x;
    s[t] = (t < nb) ? partials[t] : 0;
    __syncthreads();
    for (int off = 1; off < 256; off <<= 1) {
        int add = (t >= off) ? s[t - off] : 0;
        __syncthreads();
        s[t] += add;
        __syncthreads();
    }
    if (t < nb) partials[t] = s[t];
}

__global__ void finalize_kernel(const int* __restrict__ deg, const int* __restrict__ scanned,
                                const int* __restrict__ partials, int* __restrict__ rowstart,
                                int* __restrict__ cursor, int n) {
    const int i = blockIdx.x * 256 + threadIdx.x;
    if (i >= n) return;
    int off = (blockIdx.x > 0) ? partials[blockIdx.x - 1] : 0;
    int excl = scanned[i] - deg[i] + off;
    rowstart[i] = excl;
    cursor[i] = excl;
}

__global__ void bucket_kernel(const int* __restrict__ src, const int* __restrict__ dst,
                              int* __restrict__ cursor, int* __restrict__ srcs, int E) {
    int e = blockIdx.x * 256 + threadIdx.x;
    if (e < E) {
        int pos = atomicAdd(&cursor[dst[e]], 1);
        srcs[pos] = src[e];
    }
}

// ---- aggregation: 16 lanes/node, packed-u16 running max over CSR row ----
// valid because P >= 0 (post-ReLU bf16): uint16 order == float order; deg==0 -> 0.
__global__ void aggregate_bf16(const int* __restrict__ rowstart, const int* __restrict__ deg,
                               const int* __restrict__ srcs, const u16x8* __restrict__ P8,
                               u16x8* __restrict__ A8, int n) {
    int gid = blockIdx.x * 256 + threadIdx.x;
    int node = gid >> 4;
    if (node >= n) return;
    int q = gid & 15;
    int start = rowstart[node];
    int d = deg[node];
    u16x8 m = {0, 0, 0, 0, 0, 0, 0, 0};
    if (d > 0) {
        int s = srcs[start];
        u16x8 v = P8[(size_t)s * 16 + q];
        for (int j = 1; j < d; ++j) {
            int s1 = srcs[start + j];              // broadcast across 16 lanes
            u16x8 v1 = P8[(size_t)s1 * 16 + q];    // prefetch next row
            m = __builtin_elementwise_max(m, v);
            v = v1;
        }
        m = __builtin_elementwise_max(m, v);
    }
    A8[(size_t)node * 16 + q] = m;
}

extern "C" void kernel_launch(void* const* d_in, const int* in_sizes, int n_in,
                              void* d_out, int out_size, void* d_ws, size_t ws_size,
                              hipStream_t stream) {
    const float* x   = (const float*)d_in[0];
    const int*   ei  = (const int*)d_in[1];
    const float* Wp1 = (const float*)d_in[2];
    const float* bp1 = (const float*)d_in[3];
    const float* Wu1 = (const float*)d_in[4];
    const float* bu1 = (const float*)d_in[5];
    const float* Wp2 = (const float*)d_in[6];
    const float* bp2 = (const float*)d_in[7];
    const float* Wu2 = (const float*)d_in[8];
    const float* bu2 = (const float*)d_in[9];
    float* out = (float*)d_out;

    const int n = in_sizes[0] / D;   // 50000
    const int E = in_sizes[1] / 2;   // 600000
    const int* src = ei;
    const int* dst = ei + E;

    // workspace layout (all 16B-aligned)
    unsigned short* xb   = (unsigned short*)d_ws;        // [n,128] bf16
    unsigned short* Pb   = xb + (size_t)n * D;
    unsigned short* Ab   = Pb + (size_t)n * D;
    unsigned short* Hb   = Ab + (size_t)n * D;
    unsigned short* Wp1p = Hb + (size_t)n * D;           // 128*128
    unsigned short* Wu1p = Wp1p + D * D;                 // 256*128
    unsigned short* Wp2p = Wu1p + 2 * D * D;
    unsigned short* Wu2p = Wp2p + D * D;
    int* deg      = (int*)(Wu2p + 2 * D * D);
    int* scanned  = deg + n;
    int* rowstart = scanned + n;
    int* cursor   = rowstart + n;
    int* partials = cursor + n;                          // [256]
    int* srcs     = partials + 256;                      // [E]

    const int gb = (n + 63) / 64;          // GEMM blocks (64 rows each)
    const int nb = (n + 255) / 256;
    const int eb = (E + 255) / 256;
    const int ab = (n * 16 + 255) / 256;   // aggregate blocks
    const int cb = (n * D / 4 + 255) / 256;

    // ---- prep: x -> bf16, pack weights, build CSR ----
    conv_bf16<<<cb, 256, 0, stream>>>((const float4*)x, (ushort4*)xb, n * D / 4);
    pack_w<<<4 * 8, 64, 0, stream>>>(Wp1, Wp1p);
    pack_w<<<8 * 8, 64, 0, stream>>>(Wu1, Wu1p);
    pack_w<<<4 * 8, 64, 0, stream>>>(Wp2, Wp2p);
    pack_w<<<8 * 8, 64, 0, stream>>>(Wu2, Wu2p);

    hipMemsetAsync(deg, 0, (size_t)n * sizeof(int), stream);
    hist_kernel<<<eb, 256, 0, stream>>>(dst, deg, E);
    scan1_kernel<<<nb, 256, 0, stream>>>(deg, scanned, partials, n);
    scan2_kernel<<<1, 256, 0, stream>>>(partials, nb);
    finalize_kernel<<<nb, 256, 0, stream>>>(deg, scanned, partials, rowstart, cursor, n);
    bucket_kernel<<<eb, 256, 0, stream>>>(src, dst, cursor, srcs, E);

    // ---- layer 1 ----
    mfma_gemm<4, false><<<gb, 256, 0, stream>>>(xb, nullptr, Wp1p, bp1, Pb, n);
    aggregate_bf16<<<ab, 256, 0, stream>>>(rowstart, deg, srcs, (const u16x8*)Pb, (u16x8*)Ab, n);
    mfma_gemm<8, false><<<gb, 256, 0, stream>>>(xb, Ab, Wu1p, bu1, Hb, n);

    // ---- layer 2 ----
    mfma_gemm<4, false><<<gb, 256, 0, stream>>>(Hb, nullptr, Wp2p, bp2, Pb, n);
    aggregate_bf16<<<ab, 256, 0, stream>>>(rowstart, deg, srcs, (const u16x8*)Pb, (u16x8*)Ab, n);
    mfma_gemm<8, true><<<gb, 256, 0, stream>>>(Hb, Ab, Wu2p, bu2, out, n);
}

// Round 5
// 176.450 us; speedup vs baseline: 6.2613x; 1.0655x over previous
//
#include <hip/hip_runtime.h>

#define D 128  // D_IN = D_HID = D_OUT = 128

typedef __attribute__((ext_vector_type(8))) short bf16x8;
typedef __attribute__((ext_vector_type(4))) float f32x4;
typedef __attribute__((ext_vector_type(8))) unsigned short u16x8;

__device__ __forceinline__ unsigned short f2bf(float f) {   // RNE f32->bf16
    unsigned u = __float_as_uint(f);
    u = u + 0x7fffu + ((u >> 16) & 1u);
    return (unsigned short)(u >> 16);
}

// ---- pack one (kt,nt) group of W [K,128] f32 into per-lane MFMA B-fragment order ----
__device__ __forceinline__ void pack_one(const float* __restrict__ W,
                                         unsigned short* __restrict__ out, int g, int l) {
    const int kt = g >> 3, nt = g & 7;
    u16x8 pv;
#pragma unroll
    for (int j = 0; j < 8; ++j)
        pv[j] = f2bf(W[(size_t)(kt * 32 + (l >> 4) * 8 + j) * D + nt * 16 + (l & 15)]);
    *(u16x8*)&out[((size_t)g * 64 + l) * 8] = pv;
}

// ---- prep: conv x->bf16 | pack 4 weights | degree histogram, by blockIdx range ----
__global__ void prep_kernel(const float4* __restrict__ x4, ushort4* __restrict__ xb4, int n4,
                            const float* __restrict__ Wp1, const float* __restrict__ Wu1,
                            const float* __restrict__ Wp2, const float* __restrict__ Wu2,
                            unsigned short* __restrict__ Wp1p, unsigned short* __restrict__ Wu1p,
                            unsigned short* __restrict__ Wp2p, unsigned short* __restrict__ Wu2p,
                            const int* __restrict__ dst, int* __restrict__ deg, int E,
                            int CB, int PB) {
    int b = blockIdx.x;
    const int t = threadIdx.x;
    if (b < CB) {
        int i = b * 256 + t;
        if (i < n4) {
            float4 v = x4[i];
            ushort4 o;
            o.x = f2bf(v.x); o.y = f2bf(v.y); o.z = f2bf(v.z); o.w = f2bf(v.w);
            xb4[i] = o;
        }
        return;
    }
    b -= CB;
    if (b < PB) {
        int g = b * 4 + (t >> 6);
        int l = t & 63;
        if (g < 32)       pack_one(Wp1, Wp1p, g, l);
        else if (g < 96)  pack_one(Wu1, Wu1p, g - 32, l);
        else if (g < 128) pack_one(Wp2, Wp2p, g - 96, l);
        else              pack_one(Wu2, Wu2p, g - 128, l);
        return;
    }
    b -= PB;
    int e = b * 256 + t;
    if (e < E) atomicAdd(&deg[dst[e]], 1);
}

// ---- CSR scan ----
__global__ void scan1_kernel(const int* __restrict__ deg, int* __restrict__ scanned,
                             int* __restrict__ partials, int n) {
    __shared__ int s[256];
    const int t = threadIdx.x;
    const int i = blockIdx.x * 256 + t;
    s[t] = (i < n) ? deg[i] : 0;
    __syncthreads();
    for (int off = 1; off < 256; off <<= 1) {
        int add = (t >= off) ? s[t - off] : 0;
        __syncthreads();
        s[t] += add;
        __syncthreads();
    }
    if (i < n) scanned[i] = s[t];
    if (t == 255) partials[blockIdx.x] = s[255];
}

// finalize with inline scan of partials (nb <= 256)
__global__ void finalize2_kernel(const int* __restrict__ deg, const int* __restrict__ scanned,
                                 const int* __restrict__ partials, int* __restrict__ rowstart,
                                 int* __restrict__ cursor, int n, int nb) {
    __shared__ int s[256];
    const int t = threadIdx.x;
    s[t] = (t < nb) ? partials[t] : 0;
    __syncthreads();
    for (int off = 1; off < 256; off <<= 1) {
        int add = (t >= off) ? s[t - off] : 0;
        __syncthreads();
        s[t] += add;
        __syncthreads();
    }
    const int i = blockIdx.x * 256 + t;
    if (i >= n) return;
    int off = (blockIdx.x > 0) ? s[blockIdx.x - 1] : 0;
    int excl = scanned[i] - deg[i] + off;
    rowstart[i] = excl;
    cursor[i] = excl;
}

__global__ void bucket_kernel(const int* __restrict__ src, const int* __restrict__ dst,
                              int* __restrict__ cursor, int* __restrict__ srcs, int E) {
    int e = blockIdx.x * 256 + threadIdx.x;
    if (e < E) {
        int pos = atomicAdd(&cursor[dst[e]], 1);
        srcs[pos] = src[e];
    }
}

// ---- standalone pool GEMM (layer 1): Pb = ReLU(xb * Wp1 + bp1), bf16 out ----
__launch_bounds__(256)
__global__ void pool_mfma(const unsigned short* __restrict__ X0,
                          const unsigned short* __restrict__ Wp,
                          const float* __restrict__ bias,
                          unsigned short* __restrict__ OUT, int n) {
    __shared__ unsigned short tlds[4][16 * D];
    const int t = threadIdx.x, w = t >> 6, l = t & 63;
    const int lrow = l & 15, lk = l >> 4;
    const int r0 = blockIdx.x * 64 + w * 16;
    int arow = r0 + lrow;
    if (arow > n - 1) arow = n - 1;

    f32x4 acc[8];
#pragma unroll
    for (int nt = 0; nt < 8; ++nt) {
        float bv = bias[nt * 16 + lrow];
        acc[nt] = (f32x4){bv, bv, bv, bv};
    }
#pragma unroll
    for (int kt = 0; kt < 4; ++kt) {
        bf16x8 a = *(const bf16x8*)(X0 + (size_t)arow * D + kt * 32 + lk * 8);
#pragma unroll
        for (int nt = 0; nt < 8; ++nt) {
            bf16x8 b = *(const bf16x8*)(Wp + (((size_t)kt * 8 + nt) * 64 + l) * 8);
            acc[nt] = __builtin_amdgcn_mfma_f32_16x16x32_bf16(a, b, acc[nt], 0, 0, 0);
        }
    }
    unsigned short* tt = tlds[w];
#pragma unroll
    for (int nt = 0; nt < 8; ++nt)
#pragma unroll
        for (int r = 0; r < 4; ++r)
            tt[(lk * 4 + r) * D + nt * 16 + lrow] = f2bf(fmaxf(acc[nt][r], 0.f));
    __syncthreads();
#pragma unroll
    for (int p = 0; p < 4; ++p) {
        int flat = p * 512 + l * 8;
        int rt = flat >> 7, col = flat & (D - 1);
        int grow = r0 + rt;
        if (grow < n)
            *(u16x8*)(OUT + (size_t)grow * D + col) = *(const u16x8*)(tt + flat);
    }
}

// ---- aggregation into swizzled LDS tile [64][128] bf16 (rows = block-local nodes) ----
// swizzle: elem_col' = col ^ ((row&7)<<3)  (keeps 8-elem chunks aligned; MFMA reads 2-way free)
__device__ __forceinline__ void agg_to_lds(const int* __restrict__ rowstart,
                                           const int* __restrict__ deg,
                                           const int* __restrict__ srcs,
                                           const u16x8* __restrict__ P8,
                                           unsigned short* __restrict__ A_s,
                                           int n, int t, int base) {
    const int nl = t >> 2;          // block-local node 0..63
    const int q = t & 3;            // column quarter (32 elems)
    const int gn = base + nl;
    u16x8 m[4];
#pragma unroll
    for (int c = 0; c < 4; ++c) m[c] = (u16x8){0, 0, 0, 0, 0, 0, 0, 0};
    if (gn < n) {
        const int st = rowstart[gn];
        const int d = deg[gn];
        if (d > 0) {
            const u16x8* pr = P8 + (size_t)srcs[st] * 16 + q * 4;
            u16x8 v0 = pr[0], v1 = pr[1], v2 = pr[2], v3 = pr[3];
            for (int j = 1; j < d; ++j) {
                const u16x8* pn = P8 + (size_t)srcs[st + j] * 16 + q * 4;
                u16x8 w0 = pn[0], w1 = pn[1], w2 = pn[2], w3 = pn[3];
                m[0] = __builtin_elementwise_max(m[0], v0);
                m[1] = __builtin_elementwise_max(m[1], v1);
                m[2] = __builtin_elementwise_max(m[2], v2);
                m[3] = __builtin_elementwise_max(m[3], v3);
                v0 = w0; v1 = w1; v2 = w2; v3 = w3;
            }
            m[0] = __builtin_elementwise_max(m[0], v0);
            m[1] = __builtin_elementwise_max(m[1], v1);
            m[2] = __builtin_elementwise_max(m[2], v2);
            m[3] = __builtin_elementwise_max(m[3], v3);
        }
    }
#pragma unroll
    for (int c = 0; c < 4; ++c) {
        int col = q * 32 + c * 8;
        *(u16x8*)&A_s[nl * D + (col ^ ((nl & 7) << 3))] = m[c];
    }
}

__device__ __forceinline__ bf16x8 lds_afrag(const unsigned short* __restrict__ S,
                                            int row, int kbase) {
    return *(const bf16x8*)&S[row * D + (kbase ^ ((row & 7) << 3))];
}

// ---- fused: agg1(LDS) + upd1 GEMM -> Hb, then pool2 GEMM -> P2b ----
__launch_bounds__(256)
__global__ void fused_upd_pool(const unsigned short* __restrict__ xb,
                               const u16x8* __restrict__ Pb8,
                               const unsigned short* __restrict__ Wu1p, const float* __restrict__ bu1,
                               const unsigned short* __restrict__ Wp2p, const float* __restrict__ bp2,
                               const int* __restrict__ rowstart, const int* __restrict__ deg,
                               const int* __restrict__ srcs,
                               unsigned short* __restrict__ Hb, unsigned short* __restrict__ P2b,
                               int n) {
    __shared__ unsigned short A_s[64 * D];   // agg tile (swizzled); reused as P2 epilogue
    __shared__ unsigned short H_s[64 * D];   // H tile (swizzled)
    const int t = threadIdx.x, w = t >> 6, l = t & 63;
    const int base = blockIdx.x * 64;
    const int lrow = l & 15, lk = l >> 4;

    agg_to_lds(rowstart, deg, srcs, Pb8, A_s, n, t, base);
    __syncthreads();

    const int r0 = base + w * 16;
    int arow = r0 + lrow;
    if (arow > n - 1) arow = n - 1;

    // GEMM1: H = ReLU([x ; A] * Wu1 + bu1)
    f32x4 acc[8];
#pragma unroll
    for (int nt = 0; nt < 8; ++nt) {
        float bv = bu1[nt * 16 + lrow];
        acc[nt] = (f32x4){bv, bv, bv, bv};
    }
#pragma unroll
    for (int kt = 0; kt < 4; ++kt) {
        bf16x8 a = *(const bf16x8*)(xb + (size_t)arow * D + kt * 32 + lk * 8);
#pragma unroll
        for (int nt = 0; nt < 8; ++nt) {
            bf16x8 b = *(const bf16x8*)(Wu1p + (((size_t)kt * 8 + nt) * 64 + l) * 8);
            acc[nt] = __builtin_amdgcn_mfma_f32_16x16x32_bf16(a, b, acc[nt], 0, 0, 0);
        }
    }
#pragma unroll
    for (int kt = 4; kt < 8; ++kt) {
        bf16x8 a = lds_afrag(A_s, w * 16 + lrow, (kt - 4) * 32 + lk * 8);
#pragma unroll
        for (int nt = 0; nt < 8; ++nt) {
            bf16x8 b = *(const bf16x8*)(Wu1p + (((size_t)kt * 8 + nt) * 64 + l) * 8);
            acc[nt] = __builtin_amdgcn_mfma_f32_16x16x32_bf16(a, b, acc[nt], 0, 0, 0);
        }
    }
    // H -> swizzled LDS (bf16 + ReLU)
#pragma unroll
    for (int nt = 0; nt < 8; ++nt)
#pragma unroll
        for (int r = 0; r < 4; ++r) {
            int row = w * 16 + lk * 4 + r;
            int col = nt * 16 + lrow;
            H_s[row * D + (col ^ ((row & 7) << 3))] = f2bf(fmaxf(acc[nt][r], 0.f));
        }
    __syncthreads();

    // Hb global store (coalesced, unswizzle)
#pragma unroll
    for (int p = 0; p < 4; ++p) {
        int flat = p * 512 + l * 8;
        int rt = flat >> 7, col = flat & (D - 1);
        int grow = r0 + rt;
        if (grow < n)
            *(u16x8*)(Hb + (size_t)grow * D + col) =
                *(const u16x8*)&H_s[(w * 16 + rt) * D + (col ^ ((rt & 7) << 3))];
    }

    // GEMM2: P2 = ReLU(H * Wp2 + bp2)
    f32x4 acc2[8];
#pragma unroll
    for (int nt = 0; nt < 8; ++nt) {
        float bv = bp2[nt * 16 + lrow];
        acc2[nt] = (f32x4){bv, bv, bv, bv};
    }
#pragma unroll
    for (int kt = 0; kt < 4; ++kt) {
        bf16x8 a = lds_afrag(H_s, w * 16 + lrow, kt * 32 + lk * 8);
#pragma unroll
        for (int nt = 0; nt < 8; ++nt) {
            bf16x8 b = *(const bf16x8*)(Wp2p + (((size_t)kt * 8 + nt) * 64 + l) * 8);
            acc2[nt] = __builtin_amdgcn_mfma_f32_16x16x32_bf16(a, b, acc2[nt], 0, 0, 0);
        }
    }
    // P2 epilogue via A_s reuse (per-wave 16x128 region, linear)
    unsigned short* tt = A_s + w * 16 * D;
#pragma unroll
    for (int nt = 0; nt < 8; ++nt)
#pragma unroll
        for (int r = 0; r < 4; ++r)
            tt[(lk * 4 + r) * D + nt * 16 + lrow] = f2bf(fmaxf(acc2[nt][r], 0.f));
    __syncthreads();
#pragma unroll
    for (int p = 0; p < 4; ++p) {
        int flat = p * 512 + l * 8;
        int rt = flat >> 7, col = flat & (D - 1);
        int grow = r0 + rt;
        if (grow < n)
            *(u16x8*)(P2b + (size_t)grow * D + col) = *(const u16x8*)(tt + flat);
    }
}

// ---- fused: agg2(LDS) + upd2 GEMM -> out (f32) ----
__launch_bounds__(256)
__global__ void fused_upd2(const unsigned short* __restrict__ Hb,
                           const u16x8* __restrict__ P2b8,
                           const unsigned short* __restrict__ Wu2p, const float* __restrict__ bu2,
                           const int* __restrict__ rowstart, const int* __restrict__ deg,
                           const int* __restrict__ srcs,
                           float* __restrict__ out, int n) {
    __shared__ unsigned short A_s[64 * D];
    __shared__ float T_s[4][16 * D];
    const int t = threadIdx.x, w = t >> 6, l = t & 63;
    const int base = blockIdx.x * 64;
    const int lrow = l & 15, lk = l >> 4;

    agg_to_lds(rowstart, deg, srcs, P2b8, A_s, n, t, base);
    __syncthreads();

    const int r0 = base + w * 16;
    int arow = r0 + lrow;
    if (arow > n - 1) arow = n - 1;

    f32x4 acc[8];
#pragma unroll
    for (int nt = 0; nt < 8; ++nt) {
        float bv = bu2[nt * 16 + lrow];
        acc[nt] = (f32x4){bv, bv, bv, bv};
    }
#pragma unroll
    for (int kt = 0; kt < 4; ++kt) {
        bf16x8 a = *(const bf16x8*)(Hb + (size_t)arow * D + kt * 32 + lk * 8);
#pragma unroll
        for (int nt = 0; nt < 8; ++nt) {
            bf16x8 b = *(const bf16x8*)(Wu2p + (((size_t)kt * 8 + nt) * 64 + l) * 8);
            acc[nt] = __builtin_amdgcn_mfma_f32_16x16x32_bf16(a, b, acc[nt], 0, 0, 0);
        }
    }
#pragma unroll
    for (int kt = 4; kt < 8; ++kt) {
        bf16x8 a = lds_afrag(A_s, w * 16 + lrow, (kt - 4) * 32 + lk * 8);
#pragma unroll
        for (int nt = 0; nt < 8; ++nt) {
            bf16x8 b = *(const bf16x8*)(Wu2p + (((size_t)kt * 8 + nt) * 64 + l) * 8);
            acc[nt] = __builtin_amdgcn_mfma_f32_16x16x32_bf16(a, b, acc[nt], 0, 0, 0);
        }
    }
    float* tt = T_s[w];
#pragma unroll
    for (int nt = 0; nt < 8; ++nt)
#pragma unroll
        for (int r = 0; r < 4; ++r)
            tt[(lk * 4 + r) * D + nt * 16 + lrow] = fmaxf(acc[nt][r], 0.f);
    __syncthreads();
#pragma unroll
    for (int p = 0; p < 8; ++p) {
        int flat = p * 256 + l * 4;
        int rt = flat >> 7, col = flat & (D - 1);
        int grow = r0 + rt;
        if (grow < n)
            *(float4*)(out + (size_t)grow * D + col) = *(const float4*)(tt + flat);
    }
}

extern "C" void kernel_launch(void* const* d_in, const int* in_sizes, int n_in,
                              void* d_out, int out_size, void* d_ws, size_t ws_size,
                              hipStream_t stream) {
    const float* x   = (const float*)d_in[0];
    const int*   ei  = (const int*)d_in[1];
    const float* Wp1 = (const float*)d_in[2];
    const float* bp1 = (const float*)d_in[3];
    const float* Wu1 = (const float*)d_in[4];
    const float* bu1 = (const float*)d_in[5];
    const float* Wp2 = (const float*)d_in[6];
    const float* bp2 = (const float*)d_in[7];
    const float* Wu2 = (const float*)d_in[8];
    const float* bu2 = (const float*)d_in[9];
    float* out = (float*)d_out;

    const int n = in_sizes[0] / D;   // 50000
    const int E = in_sizes[1] / 2;   // 600000
    const int* src = ei;
    const int* dst = ei + E;

    // workspace layout (16B-aligned)
    unsigned short* xb   = (unsigned short*)d_ws;        // [n,128] bf16
    unsigned short* Pb   = xb + (size_t)n * D;
    unsigned short* Hb   = Pb + (size_t)n * D;
    unsigned short* P2b  = Hb + (size_t)n * D;
    unsigned short* Wp1p = P2b + (size_t)n * D;          // 128*128
    unsigned short* Wu1p = Wp1p + D * D;                 // 256*128
    unsigned short* Wp2p = Wu1p + 2 * D * D;
    unsigned short* Wu2p = Wp2p + D * D;
    int* deg      = (int*)(Wu2p + 2 * D * D);
    int* scanned  = deg + n;
    int* rowstart = scanned + n;
    int* cursor   = rowstart + n;
    int* partials = cursor + n;                          // [256]
    int* srcs     = partials + 256;                      // [E]

    const int gb = (n + 63) / 64;
    const int nb = (n + 255) / 256;
    const int eb = (E + 255) / 256;
    const int CB = (n * D / 4 + 255) / 256;              // conv blocks
    const int PB = 48;                                   // pack blocks (192 groups / 4)

    hipMemsetAsync(deg, 0, (size_t)n * sizeof(int), stream);
    prep_kernel<<<CB + PB + eb, 256, 0, stream>>>(
        (const float4*)x, (ushort4*)xb, n * D / 4,
        Wp1, Wu1, Wp2, Wu2, Wp1p, Wu1p, Wp2p, Wu2p, dst, deg, E, CB, PB);
    scan1_kernel<<<nb, 256, 0, stream>>>(deg, scanned, partials, n);
    finalize2_kernel<<<nb, 256, 0, stream>>>(deg, scanned, partials, rowstart, cursor, n, nb);
    bucket_kernel<<<eb, 256, 0, stream>>>(src, dst, cursor, srcs, E);

    pool_mfma<<<gb, 256, 0, stream>>>(xb, Wp1p, bp1, Pb, n);
    fused_upd_pool<<<gb, 256, 0, stream>>>(xb, (const u16x8*)Pb, Wu1p, bu1, Wp2p, bp2,
                                           rowstart, deg, srcs, Hb, P2b, n);
    fused_upd2<<<gb, 256, 0, stream>>>(Hb, (const u16x8*)P2b, Wu2p, bu2,
                                       rowstart, deg, srcs, out, n);
}